// Round 2
// baseline (374.903 us; speedup 1.0000x reference)
//
#include <hip/hip_runtime.h>
#include <math.h>

#define NSEG   1024
#define DFEAT  128
#define EPS_F  1e-6f
#define NBLK_A 2048   // phase-A blocks; 2048 x 4 waves = 8192 waves = exact chip residency
#define THR_A  256    // 4 waves = 8 half-waves per block

// ps = softplus(ps_raw), with the reference's Threshold(-50) quirk:
// sp >= 50 -> ps = -50 (never triggers for N(0,1) inputs, kept for exactness)
__device__ __forceinline__ float softplus_thr(float v) {
    float sp = log1pf(__expf(v));
    return (sp >= 50.0f) ? -50.0f : sp;
}

// ---------------------------------------------------------------------------
// Phase A: perfectly-balanced chunked segment-sum of |x|^p.
// Block k owns rows [k*chunk, (k+1)*chunk): FIXED work per block -> no tail.
// batch is sorted, so a chunk sees segments idF..idL. Contributions to idF/idL
// (shared with neighbor chunks) go to per-chunk partial vectors pcF/pcL;
// segments strictly inside the chunk (exclusively owned; none for this input)
// are zeroed by this block then atomically accumulated into sMid.
// Half-wave h (32 lanes, float4/lane = one full row) streams rows r0+h+8i.
// ---------------------------------------------------------------------------
__global__ __launch_bounds__(THR_A, 8)
void segsum_chunk_kernel(const float* __restrict__ x,
                         const int*   __restrict__ batch,
                         const float* __restrict__ ps_raw,
                         float* __restrict__ pcF,    // [NBLK_A][DFEAT]
                         float* __restrict__ pcL,    // [NBLK_A][DFEAT]
                         int*   __restrict__ idFL,   // [NBLK_A][2]
                         float* __restrict__ sMid,   // [NSEG][DFEAT]
                         int n_nodes, int chunk)
{
    const int k   = blockIdx.x;
    const int tid = threadIdx.x;
    const int hw  = tid >> 5;        // half-wave 0..7
    const int f4  = tid & 31;        // feature quad (features 4*f4 .. 4*f4+3)
    const int r0  = k * chunk;

    if (r0 >= n_nodes) {             // trailing empty chunk
        if (tid == 0) { idFL[2 * k] = -1; idFL[2 * k + 1] = -1; }
        return;
    }
    const int r1  = min(r0 + chunk, n_nodes);
    const int idF = batch[r0];
    const int idL = batch[r1 - 1];
    if (tid == 0) { idFL[2 * k] = idF; idFL[2 * k + 1] = idL; }

    // Zero exclusively-owned middle segments (general-correctness path; the
    // real input has segments > chunk so this loop body never executes).
    for (int sg = idF + 1 + hw; sg < idL; sg += 8) {
        float4* p = (float4*)&sMid[(size_t)sg * DFEAT];
        p[f4] = make_float4(0.f, 0.f, 0.f, 0.f);
    }
    __syncthreads();   // order the zeroing before this block's atomics

    // Feature quad sits entirely in one half of D -> p is lane-constant.
    const float p = softplus_thr(ps_raw[(f4 < 16) ? 0 : 1]);
    const float4* __restrict__ x4 = (const float4*)x;   // row = 32 float4

    float4 aF  = make_float4(0.f, 0.f, 0.f, 0.f);   // partial for segment idF
    float4 aL  = make_float4(0.f, 0.f, 0.f, 0.f);   // partial for segment idL
    float4 acc = make_float4(0.f, 0.f, 0.f, 0.f);   // current-run accumulator

    auto flush = [&](int seg) {
        if (seg == idF) {
            aF.x += acc.x; aF.y += acc.y; aF.z += acc.z; aF.w += acc.w;
        } else if (seg == idL) {
            aL.x += acc.x; aL.y += acc.y; aL.z += acc.z; aL.w += acc.w;
        } else {                         // middle segment: exclusive owner
            float* base = &sMid[(size_t)seg * DFEAT + 4 * f4];
            atomicAdd(base + 0, acc.x); atomicAdd(base + 1, acc.y);
            atomicAdd(base + 2, acc.z); atomicAdd(base + 3, acc.w);
        }
        acc = make_float4(0.f, 0.f, 0.f, 0.f);
    };

    int rfirst = r0 + hw;
    int cur = (rfirst < r1) ? batch[rfirst] : idF;

#pragma unroll 2
    for (int r = rfirst; r < r1; r += 8) {
        const int sg = batch[r];                    // 32-lane broadcast load
        if (sg != cur) { flush(cur); cur = sg; }    // rare (~1 per chunk)
        const float4 v = x4[(size_t)r * 32 + f4];
        acc.x += __expf(p * __logf(fabsf(v.x) + EPS_F));   // |x|^p
        acc.y += __expf(p * __logf(fabsf(v.y) + EPS_F));
        acc.z += __expf(p * __logf(fabsf(v.z) + EPS_F));
        acc.w += __expf(p * __logf(fabsf(v.w) + EPS_F));
    }
    flush(cur);

    // Reduce the 8 half-wave partials for idF/idL in LDS, write chunk partials.
    __shared__ float pFs[8][DFEAT];
    __shared__ float pLs[8][DFEAT];
    *(float4*)&pFs[hw][4 * f4] = aF;
    *(float4*)&pLs[hw][4 * f4] = aL;
    __syncthreads();

    if (tid < DFEAT) {
        float sF = 0.f, sL = 0.f;
#pragma unroll
        for (int j = 0; j < 8; ++j) { sF += pFs[j][tid]; sL += pLs[j][tid]; }
        pcF[(size_t)k * DFEAT + tid] = sF;
        pcL[(size_t)k * DFEAT + tid] = sL;
    }
}

// ---------------------------------------------------------------------------
// Phase B: one block per segment. Binary-search the contiguous row range
// (n = end-start for free), gather the 2-3 chunk partials, finalize
// g = s^(1/p) * n^(-q0), then out[b] = g @ W.T + bias (W is 64KB, L2-resident).
// ---------------------------------------------------------------------------
__global__ __launch_bounds__(128)
void finalize_gemm_kernel(const int*   __restrict__ batch,
                          const float* __restrict__ pcF,
                          const float* __restrict__ pcL,
                          const int*   __restrict__ idFL,
                          const float* __restrict__ sMid,
                          const float* __restrict__ ps_raw,
                          const float* __restrict__ qs_raw,
                          const float* __restrict__ W,
                          const float* __restrict__ bias,
                          float* __restrict__ out,
                          int n_nodes, int chunk, int nblk)
{
    const int b = blockIdx.x;
    const int i = threadIdx.x;      // 0..127

    // Two interleaved lower_bound searches (block-uniform -> scalar unit).
    int lo0 = 0, hi0 = n_nodes, lo1 = 0, hi1 = n_nodes;
    while (lo0 < hi0) { int m = (lo0 + hi0) >> 1; if (batch[m] < b)     lo0 = m + 1; else hi0 = m; }
    while (lo1 < hi1) { int m = (lo1 + hi1) >> 1; if (batch[m] < b + 1) lo1 = m + 1; else hi1 = m; }
    const int start = lo0, end = lo1;

    float ssum = 0.f;
    if (end > start) {
        const int ks = start / chunk;
        const int ke = (end - 1) / chunk;
        for (int k = ks; k <= ke && k < nblk; ++k) {
            const int f = idFL[2 * k], l = idFL[2 * k + 1];
            if (f == b)                 ssum += pcF[(size_t)k * DFEAT + i];
            else if (f < b && b < l)    ssum += sMid[(size_t)b * DFEAT + i];
            if (l == b && l != f)       ssum += pcL[(size_t)k * DFEAT + i];
        }
    }

    __shared__ float g[DFEAT];
    const float pf = softplus_thr(ps_raw[(i < 64) ? 0 : 1]);
    const float q0 = tanhf(qs_raw[0]);
    const float n  = (float)(end - start);
    // g = s^(1/p) * n^(-q0)  (single exp: exp(log(s)/p - q0*log(n)))
    g[i] = __expf(__logf(ssum) / pf - q0 * __logf(n));
    __syncthreads();

    const float4* __restrict__ W4 = (const float4*)(W + (size_t)i * DFEAT);
    const float4* g4 = (const float4*)g;        // uniform address -> LDS broadcast
    float acc = bias[i];
#pragma unroll
    for (int jj = 0; jj < DFEAT / 4; ++jj) {
        const float4 wv = W4[jj];
        const float4 gv = g4[jj];
        acc += gv.x * wv.x + gv.y * wv.y + gv.z * wv.z + gv.w * wv.w;
    }
    out[(size_t)b * DFEAT + i] = acc;
}

extern "C" void kernel_launch(void* const* d_in, const int* in_sizes, int n_in,
                              void* d_out, int out_size, void* d_ws, size_t ws_size,
                              hipStream_t stream)
{
    const float* x      = (const float*)d_in[0];
    const int*   batch  = (const int*)  d_in[1];
    const float* ps_raw = (const float*)d_in[2];
    const float* qs_raw = (const float*)d_in[3];
    const float* W      = (const float*)d_in[4];
    const float* bias   = (const float*)d_in[5];
    float*       out    = (float*)d_out;

    const int n_nodes = in_sizes[0] / DFEAT;
    const int chunk   = (n_nodes + NBLK_A - 1) / NBLK_A;   // 245 rows/block

    // Workspace layout (no memset needed: every word is written before read).
    float* pcF  = (float*)d_ws;                            // NBLK_A*DFEAT
    float* pcL  = pcF  + (size_t)NBLK_A * DFEAT;           // NBLK_A*DFEAT
    float* sMid = pcL  + (size_t)NBLK_A * DFEAT;           // NSEG*DFEAT
    int*   idFL = (int*)(sMid + (size_t)NSEG * DFEAT);     // NBLK_A*2

    segsum_chunk_kernel<<<NBLK_A, THR_A, 0, stream>>>(
        x, batch, ps_raw, pcF, pcL, idFL, sMid, n_nodes, chunk);
    finalize_gemm_kernel<<<NSEG, 128, 0, stream>>>(
        batch, pcF, pcL, idFL, sMid, ps_raw, qs_raw, W, bias, out,
        n_nodes, chunk, NBLK_A);
}

// Round 3
// 368.385 us; speedup vs baseline: 1.0177x; 1.0177x over previous
//
#include <hip/hip_runtime.h>
#include <math.h>

#define NSEG   1024
#define DFEAT  128
#define EPS_F  1e-6f
#define NBLK_A 2048   // phase-A blocks; 2048 x 4 waves = 8192 waves = exact chip residency
#define THR_A  256    // 4 waves = 8 half-waves per block

// ps = softplus(ps_raw), with the reference's Threshold(-50) quirk:
// sp >= 50 -> ps = -50 (never triggers for N(0,1) inputs, kept for exactness)
__device__ __forceinline__ float softplus_thr(float v) {
    float sp = log1pf(__expf(v));
    return (sp >= 50.0f) ? -50.0f : sp;
}

// ---------------------------------------------------------------------------
// Phase A: perfectly-balanced chunked segment-sum of |x|^p with PURE streaming.
// Block k owns rows [k*chunk, (k+1)*chunk): fixed work -> no tail imbalance.
// batch is sorted; the chunk's internal segment boundaries are found ONCE with
// ~8-step scalar binary searches, then each sub-range streams branch-free
// (float4/lane, no per-row batch reads -> full load pipelining, = R1's loop).
// Side product: segStart[s] (true global start row of segment s) is written
// exactly once across the grid -> phase B needs no searches and no memset.
// ---------------------------------------------------------------------------
__global__ __launch_bounds__(THR_A, 8)
void segsum_chunk_kernel(const float* __restrict__ x,
                         const int*   __restrict__ batch,
                         const float* __restrict__ ps_raw,
                         float* __restrict__ pcF,      // [NBLK_A][DFEAT] partial of first seg
                         float* __restrict__ pcL,      // [NBLK_A][DFEAT] partial of last seg
                         int*   __restrict__ idFL,     // [NBLK_A][2] first/last seg id
                         float* __restrict__ sMid,     // [NSEG][DFEAT] exclusive middles
                         int*   __restrict__ segStart, // [NSEG+1]
                         int n_nodes, int chunk)
{
    const int k   = blockIdx.x;
    const int tid = threadIdx.x;
    const int hw  = tid >> 5;        // half-wave 0..7
    const int f4  = tid & 31;        // feature quad (features 4*f4 .. 4*f4+3)
    const int r0  = k * chunk;
    if (r0 >= n_nodes) return;       // trailing empty chunk: never read by phase B

    const int r1   = min(r0 + chunk, n_nodes);
    const int idF  = batch[r0];
    const int idL  = batch[r1 - 1];
    const int prev = (k == 0) ? -1 : batch[r0 - 1];
    if (tid == 0) { idFL[2 * k] = idF; idFL[2 * k + 1] = idL; }

    // segStart for segments starting at r0 (incl. empty ones before idF).
    for (int s = prev + 1 + tid; s <= idF; s += THR_A) segStart[s] = r0;
    // Last non-empty chunk closes the table: segments after idL + sentinel [NSEG].
    if (r1 == n_nodes)
        for (int s = idL + 1 + tid; s <= NSEG; s += THR_A) segStart[s] = n_nodes;

    // Zero exclusively-owned middle segments (fully inside this chunk; cannot
    // occur for this input's ~488-row segments, kept for general correctness).
    for (int sg = idF + 1 + hw; sg < idL; sg += 8) {
        float4* pz = (float4*)&sMid[(size_t)sg * DFEAT];
        pz[f4] = make_float4(0.f, 0.f, 0.f, 0.f);
    }
    if (idL > idF + 1) __syncthreads();  // order zeroing before atomics below

    // Feature quad sits entirely in one half of D -> p is lane-constant.
    const float p = softplus_thr(ps_raw[(f4 < 16) ? 0 : 1]);
    const float4* __restrict__ x4 = (const float4*)x;   // row = 32 float4

    float4 aF = make_float4(0.f, 0.f, 0.f, 0.f);
    float4 aL = make_float4(0.f, 0.f, 0.f, 0.f);

    int a = r0;                              // current sub-range start
    for (int s = idF; s <= idL; ++s) {       // block-uniform loop, 1-3 iters here
        int bnd;
        if (s == idL) bnd = r1;
        else {                               // lower_bound(s+1) in (a, r1)
            int lo = a + 1, hi = r1;
            while (lo < hi) { int m = (lo + hi) >> 1; if (batch[m] < s + 1) lo = m + 1; else hi = m; }
            bnd = lo;
            if (tid == 0) segStart[s + 1] = bnd;   // true global start of seg s+1
        }

        // PURE streaming over [a, bnd): half-wave hw owns rows a+hw+8i.
        float4 acc = make_float4(0.f, 0.f, 0.f, 0.f);
#pragma unroll 2
        for (int r = a + hw; r < bnd; r += 8) {
            const float4 v = x4[(size_t)r * 32 + f4];
            acc.x += __expf(p * __logf(fabsf(v.x) + EPS_F));   // |x|^p
            acc.y += __expf(p * __logf(fabsf(v.y) + EPS_F));
            acc.z += __expf(p * __logf(fabsf(v.z) + EPS_F));
            acc.w += __expf(p * __logf(fabsf(v.w) + EPS_F));
        }

        if (s == idF) {
            aF.x += acc.x; aF.y += acc.y; aF.z += acc.z; aF.w += acc.w;
        } else if (s == idL) {
            aL.x += acc.x; aL.y += acc.y; aL.z += acc.z; aL.w += acc.w;
        } else {                             // exclusive middle segment
            float* base = &sMid[(size_t)s * DFEAT + 4 * f4];
            atomicAdd(base + 0, acc.x); atomicAdd(base + 1, acc.y);
            atomicAdd(base + 2, acc.z); atomicAdd(base + 3, acc.w);
        }
        a = bnd;
    }

    // Reduce the 8 half-wave partials for idF/idL in LDS, write chunk partials.
    __shared__ float pFs[8][DFEAT];
    __shared__ float pLs[8][DFEAT];
    *(float4*)&pFs[hw][4 * f4] = aF;
    *(float4*)&pLs[hw][4 * f4] = aL;
    __syncthreads();

    if (tid < DFEAT) {
        float sF = 0.f, sL = 0.f;
#pragma unroll
        for (int j = 0; j < 8; ++j) { sF += pFs[j][tid]; sL += pLs[j][tid]; }
        pcF[(size_t)k * DFEAT + tid] = sF;
        pcL[(size_t)k * DFEAT + tid] = sL;
    }
}

// ---------------------------------------------------------------------------
// Phase B: one block per segment. Row range comes straight from segStart
// (no searches). Gather the 2-4 chunk partials, finalize g = s^(1/p)*n^(-q0),
// then out[b] = g @ W.T + bias (W is 64 KB -> L2-resident across 1024 blocks).
// ---------------------------------------------------------------------------
__global__ __launch_bounds__(128)
void finalize_gemm_kernel(const float* __restrict__ pcF,
                          const float* __restrict__ pcL,
                          const int*   __restrict__ idFL,
                          const float* __restrict__ sMid,
                          const int*   __restrict__ segStart,
                          const float* __restrict__ ps_raw,
                          const float* __restrict__ qs_raw,
                          const float* __restrict__ W,
                          const float* __restrict__ bias,
                          float* __restrict__ out,
                          int chunk, int nblk)
{
    const int b = blockIdx.x;
    const int i = threadIdx.x;      // 0..127

    const int start = segStart[b];
    const int end   = segStart[b + 1];

    float ssum = 0.f;
    if (end > start) {
        const int ks = start / chunk;
        const int ke = (end - 1) / chunk;
        for (int k = ks; k <= ke && k < nblk; ++k) {
            const int f = idFL[2 * k], l = idFL[2 * k + 1];
            if (f == b)              ssum += pcF[(size_t)k * DFEAT + i];
            else if (f < b && b < l) ssum += sMid[(size_t)b * DFEAT + i];
            if (l == b && l != f)    ssum += pcL[(size_t)k * DFEAT + i];
        }
    }

    __shared__ float g[DFEAT];
    const float pf = softplus_thr(ps_raw[(i < 64) ? 0 : 1]);
    const float q0 = tanhf(qs_raw[0]);
    const float n  = (float)(end - start);
    // g = s^(1/p) * n^(-q0)  (single exp: exp(log(s)/p - q0*log(n)))
    g[i] = __expf(__logf(ssum) / pf - q0 * __logf(n));
    __syncthreads();

    const float4* __restrict__ W4 = (const float4*)(W + (size_t)i * DFEAT);
    const float4* g4 = (const float4*)g;        // uniform address -> LDS broadcast
    float acc = bias[i];
#pragma unroll
    for (int jj = 0; jj < DFEAT / 4; ++jj) {
        const float4 wv = W4[jj];
        const float4 gv = g4[jj];
        acc += gv.x * wv.x + gv.y * wv.y + gv.z * wv.z + gv.w * wv.w;
    }
    out[(size_t)b * DFEAT + i] = acc;
}

extern "C" void kernel_launch(void* const* d_in, const int* in_sizes, int n_in,
                              void* d_out, int out_size, void* d_ws, size_t ws_size,
                              hipStream_t stream)
{
    const float* x      = (const float*)d_in[0];
    const int*   batch  = (const int*)  d_in[1];
    const float* ps_raw = (const float*)d_in[2];
    const float* qs_raw = (const float*)d_in[3];
    const float* W      = (const float*)d_in[4];
    const float* bias   = (const float*)d_in[5];
    float*       out    = (float*)d_out;

    const int n_nodes = in_sizes[0] / DFEAT;
    const int chunk   = (n_nodes + NBLK_A - 1) / NBLK_A;   // ~245 rows/block

    // Workspace layout (every word read by phase B is written by phase A first;
    // no memset dispatch needed).
    float* pcF      = (float*)d_ws;                         // NBLK_A*DFEAT
    float* pcL      = pcF  + (size_t)NBLK_A * DFEAT;        // NBLK_A*DFEAT
    float* sMid     = pcL  + (size_t)NBLK_A * DFEAT;        // NSEG*DFEAT
    int*   idFL     = (int*)(sMid + (size_t)NSEG * DFEAT);  // NBLK_A*2
    int*   segStart = idFL + (size_t)NBLK_A * 2;            // NSEG+1

    segsum_chunk_kernel<<<NBLK_A, THR_A, 0, stream>>>(
        x, batch, ps_raw, pcF, pcL, idFL, sMid, segStart, n_nodes, chunk);
    finalize_gemm_kernel<<<NSEG, 128, 0, stream>>>(
        pcF, pcL, idFL, sMid, segStart, ps_raw, qs_raw, W, bias, out,
        chunk, NBLK_A);
}

// Round 5
// 344.743 us; speedup vs baseline: 1.0875x; 1.0686x over previous
//
#include <hip/hip_runtime.h>
#include <math.h>

#define NSEG   1024
#define DFEAT  128
#define EPS_F  1e-6f
#define NBLK_A 2048   // phase-A blocks; 2048 x 4 waves = 8192 waves = exact chip residency
#define THR_A  256    // 4 waves = 8 half-waves per block

typedef __attribute__((ext_vector_type(4))) float f32x4;

// ps = softplus(ps_raw), with the reference's Threshold(-50) quirk:
// sp >= 50 -> ps = -50 (never triggers for N(0,1) inputs, kept for exactness)
__device__ __forceinline__ float softplus_thr(float v) {
    float sp = log1pf(__expf(v));
    return (sp >= 50.0f) ? -50.0f : sp;
}

// ---------------------------------------------------------------------------
// Phase A: perfectly-balanced chunked segment-sum of |x|^p with PURE streaming.
// Block k owns rows [k*chunk, (k+1)*chunk): fixed work -> no tail imbalance.
// batch is sorted; internal segment boundaries found ONCE per chunk by scalar
// binary search, then each sub-range streams branch-free. x is read with
// NONTEMPORAL float4 loads (use-once stream; don't allocate in L2) and
// unroll 4 (deeper load pipeline). Side product: segStart[] table so phase B
// needs no searches; every workspace word is written before read (no memset).
// ---------------------------------------------------------------------------
__global__ __launch_bounds__(THR_A, 8)
void segsum_chunk_kernel(const float* __restrict__ x,
                         const int*   __restrict__ batch,
                         const float* __restrict__ ps_raw,
                         float* __restrict__ pcF,      // [NBLK_A][DFEAT] partial of first seg
                         float* __restrict__ pcL,      // [NBLK_A][DFEAT] partial of last seg
                         int*   __restrict__ idFL,     // [NBLK_A][2] first/last seg id
                         float* __restrict__ sMid,     // [NSEG][DFEAT] exclusive middles
                         int*   __restrict__ segStart, // [NSEG+1]
                         int n_nodes, int chunk)
{
    const int k   = blockIdx.x;
    const int tid = threadIdx.x;
    const int hw  = tid >> 5;        // half-wave 0..7
    const int f4  = tid & 31;        // feature quad (features 4*f4 .. 4*f4+3)
    const int r0  = k * chunk;
    if (r0 >= n_nodes) return;       // trailing empty chunk: never read by phase B

    const int r1   = min(r0 + chunk, n_nodes);
    const int idF  = batch[r0];
    const int idL  = batch[r1 - 1];
    const int prev = (k == 0) ? -1 : batch[r0 - 1];
    if (tid == 0) { idFL[2 * k] = idF; idFL[2 * k + 1] = idL; }

    // segStart for segments starting at r0 (incl. empty ones before idF).
    for (int s = prev + 1 + tid; s <= idF; s += THR_A) segStart[s] = r0;
    // Last non-empty chunk closes the table: segments after idL + sentinel.
    if (r1 == n_nodes)
        for (int s = idL + 1 + tid; s <= NSEG; s += THR_A) segStart[s] = n_nodes;

    // Zero exclusively-owned middle segments (cannot occur for ~488-row
    // segments vs 245-row chunks; kept for general correctness).
    for (int sg = idF + 1 + hw; sg < idL; sg += 8) {
        float4* pz = (float4*)&sMid[(size_t)sg * DFEAT];
        pz[f4] = make_float4(0.f, 0.f, 0.f, 0.f);
    }
    if (idL > idF + 1) __syncthreads();  // order zeroing before atomics below

    // Feature quad sits entirely in one half of D -> p is lane-constant.
    const float p = softplus_thr(ps_raw[(f4 < 16) ? 0 : 1]);
    const f32x4* __restrict__ x4 = (const f32x4*)x;   // row = 32 float4

    float4 aF = make_float4(0.f, 0.f, 0.f, 0.f);
    float4 aL = make_float4(0.f, 0.f, 0.f, 0.f);

    int a = r0;                              // current sub-range start
    for (int s = idF; s <= idL; ++s) {       // block-uniform, 1-3 iters here
        int bnd;
        if (s == idL) bnd = r1;
        else {                               // lower_bound(s+1) in (a, r1)
            int lo = a + 1, hi = r1;
            while (lo < hi) { int m = (lo + hi) >> 1; if (batch[m] < s + 1) lo = m + 1; else hi = m; }
            bnd = lo;
            if (tid == 0) segStart[s + 1] = bnd;   // true start of seg s+1
        }

        // PURE streaming over [a, bnd): half-wave hw owns rows a+hw+8i.
        // Nontemporal: use-once stream, keep it out of L2.
        float4 acc = make_float4(0.f, 0.f, 0.f, 0.f);
#pragma unroll 4
        for (int r = a + hw; r < bnd; r += 8) {
            const f32x4 v = __builtin_nontemporal_load(&x4[(size_t)r * 32 + f4]);
            acc.x += __expf(p * __logf(fabsf(v.x) + EPS_F));   // |x|^p
            acc.y += __expf(p * __logf(fabsf(v.y) + EPS_F));
            acc.z += __expf(p * __logf(fabsf(v.z) + EPS_F));
            acc.w += __expf(p * __logf(fabsf(v.w) + EPS_F));
        }

        if (s == idF) {
            aF.x += acc.x; aF.y += acc.y; aF.z += acc.z; aF.w += acc.w;
        } else if (s == idL) {
            aL.x += acc.x; aL.y += acc.y; aL.z += acc.z; aL.w += acc.w;
        } else {                             // exclusive middle segment
            float* base = &sMid[(size_t)s * DFEAT + 4 * f4];
            atomicAdd(base + 0, acc.x); atomicAdd(base + 1, acc.y);
            atomicAdd(base + 2, acc.z); atomicAdd(base + 3, acc.w);
        }
        a = bnd;
    }

    // Reduce the 8 half-wave partials for idF/idL in LDS, write chunk partials.
    __shared__ float pFs[8][DFEAT];
    __shared__ float pLs[8][DFEAT];
    *(float4*)&pFs[hw][4 * f4] = aF;
    *(float4*)&pLs[hw][4 * f4] = aL;
    __syncthreads();

    if (tid < DFEAT) {
        float sF = 0.f, sL = 0.f;
#pragma unroll
        for (int j = 0; j < 8; ++j) { sF += pFs[j][tid]; sL += pLs[j][tid]; }
        pcF[(size_t)k * DFEAT + tid] = sF;
        pcL[(size_t)k * DFEAT + tid] = sL;
    }
}

// ---------------------------------------------------------------------------
// Phase B: one block per segment. Row range straight from segStart (no
// searches). Gather the 2-4 chunk partials, finalize g = s^(1/p)*n^(-q0),
// then out[b] = g @ W.T + bias (W is 64 KB -> L2-resident across 1024 blocks).
// ---------------------------------------------------------------------------
__global__ __launch_bounds__(128)
void finalize_gemm_kernel(const float* __restrict__ pcF,
                          const float* __restrict__ pcL,
                          const int*   __restrict__ idFL,
                          const float* __restrict__ sMid,
                          const int*   __restrict__ segStart,
                          const float* __restrict__ ps_raw,
                          const float* __restrict__ qs_raw,
                          const float* __restrict__ W,
                          const float* __restrict__ bias,
                          float* __restrict__ out,
                          int chunk, int nblk)
{
    const int b = blockIdx.x;
    const int i = threadIdx.x;      // 0..127

    const int start = segStart[b];
    const int end   = segStart[b + 1];

    float ssum = 0.f;
    if (end > start) {
        const int ks = start / chunk;
        const int ke = (end - 1) / chunk;
        for (int k = ks; k <= ke && k < nblk; ++k) {
            const int f = idFL[2 * k], l = idFL[2 * k + 1];
            if (f == b)              ssum += pcF[(size_t)k * DFEAT + i];
            else if (f < b && b < l) ssum += sMid[(size_t)b * DFEAT + i];
            if (l == b && l != f)    ssum += pcL[(size_t)k * DFEAT + i];
        }
    }

    __shared__ float g[DFEAT];
    const float pf = softplus_thr(ps_raw[(i < 64) ? 0 : 1]);
    const float q0 = tanhf(qs_raw[0]);
    const float n  = (float)(end - start);
    // g = s^(1/p) * n^(-q0)  (single exp: exp(log(s)/p - q0*log(n)))
    g[i] = __expf(__logf(ssum) / pf - q0 * __logf(n));
    __syncthreads();

    const float4* __restrict__ W4 = (const float4*)(W + (size_t)i * DFEAT);
    const float4* g4 = (const float4*)g;        // uniform address -> LDS broadcast
    float acc = bias[i];
#pragma unroll
    for (int jj = 0; jj < DFEAT / 4; ++jj) {
        const float4 wv = W4[jj];
        const float4 gv = g4[jj];
        acc += gv.x * wv.x + gv.y * wv.y + gv.z * wv.z + gv.w * wv.w;
    }
    out[(size_t)b * DFEAT + i] = acc;
}

extern "C" void kernel_launch(void* const* d_in, const int* in_sizes, int n_in,
                              void* d_out, int out_size, void* d_ws, size_t ws_size,
                              hipStream_t stream)
{
    const float* x      = (const float*)d_in[0];
    const int*   batch  = (const int*)  d_in[1];
    const float* ps_raw = (const float*)d_in[2];
    const float* qs_raw = (const float*)d_in[3];
    const float* W      = (const float*)d_in[4];
    const float* bias   = (const float*)d_in[5];
    float*       out    = (float*)d_out;

    const int n_nodes = in_sizes[0] / DFEAT;
    const int chunk   = (n_nodes + NBLK_A - 1) / NBLK_A;   // ~245 rows/block

    // Workspace layout (every word read by phase B is written by phase A
    // first; no memset dispatch needed).
    float* pcF      = (float*)d_ws;                         // NBLK_A*DFEAT
    float* pcL      = pcF  + (size_t)NBLK_A * DFEAT;        // NBLK_A*DFEAT
    float* sMid     = pcL  + (size_t)NBLK_A * DFEAT;        // NSEG*DFEAT
    int*   idFL     = (int*)(sMid + (size_t)NSEG * DFEAT);  // NBLK_A*2
    int*   segStart = idFL + (size_t)NBLK_A * 2;            // NSEG+1

    segsum_chunk_kernel<<<NBLK_A, THR_A, 0, stream>>>(
        x, batch, ps_raw, pcF, pcL, idFL, sMid, segStart, n_nodes, chunk);
    finalize_gemm_kernel<<<NSEG, 128, 0, stream>>>(
        pcF, pcL, idFL, sMid, segStart, ps_raw, qs_raw, W, bias, out,
        chunk, NBLK_A);
}